// Round 1
// baseline (624.395 us; speedup 1.0000x reference)
//
#include <hip/hip_runtime.h>
#include <math.h>

#define B_  8
#define S_  512
#define D_  512
#define H_  8
#define DK_ 64
#define KL_ 1024

// ---------------------------------------------------------------------------
// Swizzled float4 LDS accessors. Logical (row, c) with c = float4-column.
// Physical f4 col = (c + (row>>2)) & mask -> row-strided column reads land on
// distinct bank groups (worst case 2-way, which is free on CDNA4 [m136]).
// ---------------------------------------------------------------------------
__device__ __forceinline__ float4& lds4_32(float (*a)[32], int row, int c) {
    return *(float4*)&a[row][((c + (row >> 2)) & 7) << 2];
}
__device__ __forceinline__ float4& lds4_64(float (*a)[64], int row, int c) {
    return *(float4*)&a[row][((c + (row >> 2)) & 15) << 2];
}

// ---------------------------------------------------------------------------
// Cache shift: k_out[:, :, 0:512, :] = prev_k[:, :, 512:1024, :], same for v.
// Also writes new_offset (=1024) as float into the last d_out element.
// ---------------------------------------------------------------------------
__global__ __launch_bounds__(256)
void copy_prev_kernel(const float4* __restrict__ pk, const float4* __restrict__ pv,
                      float4* __restrict__ kout, float4* __restrict__ vout,
                      float* __restrict__ off_out) {
    int i = blockIdx.x * 256 + threadIdx.x;     // 0 .. 524287
    int bh = i >> 13;                           // b*H+h (64)
    int r4 = i & 8191;                          // 512 rows * 16 f4
    kout[bh * 16384 + r4] = pk[bh * 16384 + 8192 + r4];
    vout[bh * 16384 + r4] = pv[bh * 16384 + 8192 + r4];
    if (i == 0) off_out[0] = 1024.0f;
}

// ---------------------------------------------------------------------------
// C = A (4096x512, row-major) @ W^T (W is 512x512 row-major) + bias.
// mode 0: C[m*512+n] (plain row-major)
// mode 1: scatter to (B,H,S,DK)  q layout
// mode 2: scatter to (B,H,KL,DK) at row 512+s (new K/V into cache output)
// ---------------------------------------------------------------------------
__device__ __forceinline__
void gemm_body(const float* __restrict__ A, const float* __restrict__ W,
               const float* __restrict__ bias, float* __restrict__ C, int mode) {
    __shared__ float As[64][32];
    __shared__ float Bs[64][32];
    const int t  = threadIdx.x;
    const int bm = blockIdx.y, bn = blockIdx.x;
    const int tm = t >> 4, tn = t & 15;
    float acc[4][4] = {};

    for (int k0 = 0; k0 < 512; k0 += 32) {
        __syncthreads();                         // protect LDS vs prev tile readers
        #pragma unroll
        for (int l = 0; l < 2; ++l) {
            int idx = t + (l << 8);              // 0..511
            int row = idx >> 3, c4 = idx & 7;
            lds4_32(As, row, c4) = *(const float4*)&A[((bm << 6) + row) * 512 + k0 + (c4 << 2)];
            lds4_32(Bs, row, c4) = *(const float4*)&W[((bn << 6) + row) * 512 + k0 + (c4 << 2)];
        }
        __syncthreads();
        #pragma unroll
        for (int kk4 = 0; kk4 < 8; ++kk4) {
            float4 a4[4], b4[4];
            #pragma unroll
            for (int i = 0; i < 4; ++i) a4[i] = lds4_32(As, tm * 4 + i, kk4);
            #pragma unroll
            for (int j = 0; j < 4; ++j) b4[j] = lds4_32(Bs, tn * 4 + j, kk4);
            #pragma unroll
            for (int i = 0; i < 4; ++i) {
                const float* ap = (const float*)&a4[i];
                #pragma unroll
                for (int j = 0; j < 4; ++j) {
                    const float* bp = (const float*)&b4[j];
                    #pragma unroll
                    for (int u = 0; u < 4; ++u)
                        acc[i][j] = fmaf(ap[u], bp[u], acc[i][j]);
                }
            }
        }
    }

    #pragma unroll
    for (int i = 0; i < 4; ++i) {
        int m = (bm << 6) + tm * 4 + i;
        #pragma unroll
        for (int j = 0; j < 4; ++j) {
            int n = (bn << 6) + tn * 4 + j;
            float val = acc[i][j] + bias[n];
            if (mode == 0) {
                C[m * 512 + n] = val;
            } else {
                int b = m >> 9, s = m & 511;
                int h = n >> 6, d = n & 63;
                if (mode == 1) C[((b * H_ + h) * S_ + s) * DK_ + d] = val;
                else           C[((b * H_ + h) * KL_ + 512 + s) * DK_ + d] = val;
            }
        }
    }
}

__global__ __launch_bounds__(256)
void qkv_gemm_kernel(const float* __restrict__ x,
                     const float* __restrict__ Wq, const float* __restrict__ bq,
                     const float* __restrict__ Wk, const float* __restrict__ bk,
                     const float* __restrict__ Wv, const float* __restrict__ bv,
                     float* __restrict__ q_ws, float* __restrict__ kout,
                     float* __restrict__ vout) {
    const float* W; const float* bias; float* C; int mode;
    if (blockIdx.z == 0)      { W = Wq; bias = bq; C = q_ws; mode = 1; }
    else if (blockIdx.z == 1) { W = Wk; bias = bk; C = kout; mode = 2; }
    else                      { W = Wv; bias = bv; C = vout; mode = 2; }
    gemm_body(x, W, bias, C, mode);
}

__global__ __launch_bounds__(256)
void out_gemm_kernel(const float* __restrict__ A, const float* __restrict__ Wo,
                     const float* __restrict__ bo, float* __restrict__ C) {
    gemm_body(A, Wo, bo, C, 0);
}

// ---------------------------------------------------------------------------
// Flash-style attention. Block = (qt, h, b): 64 queries x all keys <= 512+qg.
// Online softmax; thread (tm,tn) owns a 4x4 micro-tile. P row-trip via LDS is
// wave-private (rows tm*4+i touched only by lanes tm*16..tm*16+15).
// Q in (B,H,S,DK); K,V in (B,H,KL,DK); O written in (B,S,H,DK)=(4096x512).
// ---------------------------------------------------------------------------
__global__ __launch_bounds__(256)
void attn_kernel(const float* __restrict__ Q, const float* __restrict__ K,
                 const float* __restrict__ V, float* __restrict__ O) {
    const int qt = blockIdx.x, h = blockIdx.y, b = blockIdx.z;
    const int bh = b * H_ + h;
    const int t  = threadIdx.x;
    const int tm = t >> 4, tn = t & 15;

    __shared__ float Qs[64][64];
    __shared__ float Ks[64][64];
    __shared__ float Vs[64][64];
    __shared__ float Ps[64][64];

    const float* Qg = Q + (bh * S_ + (qt << 6)) * DK_;
    for (int idx = t; idx < 1024; idx += 256) {
        int row = idx >> 4, c4 = idx & 15;
        lds4_64(Qs, row, c4) = *(const float4*)&Qg[row * 64 + (c4 << 2)];
    }

    float m_run[4], l_run[4], acc[4][4];
    #pragma unroll
    for (int i = 0; i < 4; ++i) {
        m_run[i] = -INFINITY; l_run[i] = 0.f;
        #pragma unroll
        for (int j = 0; j < 4; ++j) acc[i][j] = 0.f;
    }

    const int ktmax = 8 + qt;                // keys <= 512 + qg  =>  tiles 0..8+qt
    for (int kt = 0; kt <= ktmax; ++kt) {
        __syncthreads();                     // prev-tile readers done (also covers Qs load)
        const float* Kg = K + (bh * KL_ + (kt << 6)) * DK_;
        const float* Vg = V + (bh * KL_ + (kt << 6)) * DK_;
        for (int idx = t; idx < 1024; idx += 256) {
            int row = idx >> 4, c4 = idx & 15;
            lds4_64(Ks, row, c4) = *(const float4*)&Kg[row * 64 + (c4 << 2)];
            lds4_64(Vs, row, c4) = *(const float4*)&Vg[row * 64 + (c4 << 2)];
        }
        __syncthreads();

        // ---- scores S = Q K^T * 1/8, micro-tile 4x4 ----
        float s[4][4] = {};
        #pragma unroll
        for (int dd4 = 0; dd4 < 16; ++dd4) {
            float4 a4[4], b4[4];
            #pragma unroll
            for (int i = 0; i < 4; ++i) a4[i] = lds4_64(Qs, tm * 4 + i, dd4);
            #pragma unroll
            for (int j = 0; j < 4; ++j) b4[j] = lds4_64(Ks, tn * 4 + j, dd4);
            #pragma unroll
            for (int i = 0; i < 4; ++i) {
                const float* ap = (const float*)&a4[i];
                #pragma unroll
                for (int j = 0; j < 4; ++j) {
                    const float* bp = (const float*)&b4[j];
                    #pragma unroll
                    for (int u = 0; u < 4; ++u)
                        s[i][j] = fmaf(ap[u], bp[u], s[i][j]);
                }
            }
        }
        const bool diag = (kt == ktmax);
        #pragma unroll
        for (int i = 0; i < 4; ++i)
            #pragma unroll
            for (int j = 0; j < 4; ++j) {
                s[i][j] *= 0.125f;           // dk^-0.5
                if (diag && (tn * 4 + j) > (tm * 4 + i)) s[i][j] = -INFINITY;
            }

        // ---- online softmax: row stats across the 16 lanes sharing tm ----
        float m_new[4], alpha[4], p[4][4];
        #pragma unroll
        for (int i = 0; i < 4; ++i) {
            float r = fmaxf(fmaxf(s[i][0], s[i][1]), fmaxf(s[i][2], s[i][3]));
            r = fmaxf(r, __shfl_xor(r, 1));
            r = fmaxf(r, __shfl_xor(r, 2));
            r = fmaxf(r, __shfl_xor(r, 4));
            r = fmaxf(r, __shfl_xor(r, 8));
            m_new[i] = fmaxf(m_run[i], r);
        }
        #pragma unroll
        for (int i = 0; i < 4; ++i) {
            float ps = 0.f;
            #pragma unroll
            for (int j = 0; j < 4; ++j) { p[i][j] = __expf(s[i][j] - m_new[i]); ps += p[i][j]; }
            ps += __shfl_xor(ps, 1);
            ps += __shfl_xor(ps, 2);
            ps += __shfl_xor(ps, 4);
            ps += __shfl_xor(ps, 8);
            alpha[i] = __expf(m_run[i] - m_new[i]);   // exp(-inf)=0 on first tile
            l_run[i] = l_run[i] * alpha[i] + ps;
            m_run[i] = m_new[i];
        }
        #pragma unroll
        for (int i = 0; i < 4; ++i) {
            float4 pv4 = make_float4(p[i][0], p[i][1], p[i][2], p[i][3]);
            lds4_64(Ps, tm * 4 + i, tn) = pv4;       // wave-private rows: no barrier
        }
        #pragma unroll
        for (int i = 0; i < 4; ++i)
            #pragma unroll
            for (int j = 0; j < 4; ++j) acc[i][j] *= alpha[i];

        // ---- O += P V, micro-tile 4x4 ----
        #pragma unroll
        for (int kc4 = 0; kc4 < 16; ++kc4) {
            float4 a4[4], b4[4];
            #pragma unroll
            for (int i = 0; i < 4; ++i) a4[i] = lds4_64(Ps, tm * 4 + i, kc4);
            #pragma unroll
            for (int u = 0; u < 4; ++u) b4[u] = lds4_64(Vs, kc4 * 4 + u, tn);
            #pragma unroll
            for (int i = 0; i < 4; ++i) {
                const float* ap = (const float*)&a4[i];
                #pragma unroll
                for (int u = 0; u < 4; ++u) {
                    const float* bp = (const float*)&b4[u];
                    #pragma unroll
                    for (int j = 0; j < 4; ++j)
                        acc[i][j] = fmaf(ap[u], bp[j], acc[i][j]);
                }
            }
        }
    }

    // epilogue: O[(b*512 + qg)*512 + h*64 + dc], (B,S,H,DK) row-major
    float* Og = O + (b * S_ + (qt << 6)) * D_ + (h << 6);
    #pragma unroll
    for (int i = 0; i < 4; ++i) {
        float inv = 1.f / l_run[i];
        float4 v = make_float4(acc[i][0] * inv, acc[i][1] * inv,
                               acc[i][2] * inv, acc[i][3] * inv);
        *(float4*)&Og[(tm * 4 + i) * D_ + tn * 4] = v;
    }
}

// ---------------------------------------------------------------------------
extern "C" void kernel_launch(void* const* d_in, const int* in_sizes, int n_in,
                              void* d_out, int out_size, void* d_ws, size_t ws_size,
                              hipStream_t stream) {
    const float* x  = (const float*)d_in[0];
    const float* pk = (const float*)d_in[1];
    const float* pv = (const float*)d_in[2];
    const float* Wq = (const float*)d_in[3];
    const float* bq = (const float*)d_in[4];
    const float* Wk = (const float*)d_in[5];
    const float* bk = (const float*)d_in[6];
    const float* Wv = (const float*)d_in[7];
    const float* bv = (const float*)d_in[8];
    const float* Wo = (const float*)d_in[9];
    const float* bo = (const float*)d_in[10];

    float* out     = (float*)d_out;            // (8,512,512)   = 2097152
    float* kout    = out + 2097152;            // (8,8,1024,64) = 4194304
    float* vout    = kout + 4194304;           // (8,8,1024,64) = 4194304
    float* off_out = vout + 4194304;           // 1 elem (float 1024.0)

    float* q_ws    = (float*)d_ws;             // 4096*512 floats = 8 MB
    float* attn_ws = q_ws + 4096 * 512;        // 4096*512 floats = 8 MB (ws >= 16 MB)

    // 1) shift cache tail + offset scalar
    copy_prev_kernel<<<2048, 256, 0, stream>>>((const float4*)pk, (const float4*)pv,
                                               (float4*)kout, (float4*)vout, off_out);
    // 2) fused QKV projections (z = 0/1/2)
    qkv_gemm_kernel<<<dim3(8, 64, 3), 256, 0, stream>>>(x, Wq, bq, Wk, bk, Wv, bv,
                                                        q_ws, kout, vout);
    // 3) attention over the assembled cache
    attn_kernel<<<dim3(8, 8, 8), 256, 0, stream>>>(q_ws, kout, vout, attn_ws);
    // 4) output projection
    out_gemm_kernel<<<dim3(8, 64), 256, 0, stream>>>(attn_ws, Wo, bo, out);
}

// Round 2
// 322.590 us; speedup vs baseline: 1.9356x; 1.9356x over previous
//
#include <hip/hip_runtime.h>
#include <math.h>

#define B_  8
#define S_  512
#define D_  512
#define H_  8
#define DK_ 64
#define KL_ 1024

typedef __attribute__((ext_vector_type(8))) short bf16x8;
typedef __attribute__((ext_vector_type(4))) float f32x4;

__device__ __forceinline__ unsigned short f2bf(float f) {
    unsigned u = __float_as_uint(f);
    u += 0x7FFF + ((u >> 16) & 1);          // RNE
    return (unsigned short)(u >> 16);
}
__device__ __forceinline__ float bf2f(unsigned short h) {
    return __uint_as_float(((unsigned)h) << 16);
}

// ---------------------------------------------------------------------------
// Swizzled float4 LDS accessor for 64x32 GEMM tiles.
// ---------------------------------------------------------------------------
__device__ __forceinline__ float4& lds4_32(float (*a)[32], int row, int c) {
    return *(float4*)&a[row][((c + (row >> 2)) & 7) << 2];
}

// ---------------------------------------------------------------------------
// Cache shift: k_out[:, :, 0:512, :] = prev_k[:, :, 512:1024, :]; same for v.
// Writes new_offset (=1024) as float.
// ---------------------------------------------------------------------------
__global__ __launch_bounds__(256)
void copy_prev_kernel(const float4* __restrict__ pk, const float4* __restrict__ pv,
                      float4* __restrict__ kout, float4* __restrict__ vout,
                      float* __restrict__ off_out) {
    int i = blockIdx.x * 256 + threadIdx.x;     // 0 .. 524287
    int bh = i >> 13;                           // b*H+h (64)
    int r4 = i & 8191;                          // 512 rows * 16 f4
    kout[bh * 16384 + r4] = pk[bh * 16384 + 8192 + r4];
    vout[bh * 16384 + r4] = pv[bh * 16384 + 8192 + r4];
    if (i == 0) off_out[0] = 1024.0f;
}

// ---------------------------------------------------------------------------
// GEMM C = A(4096x512) @ W^T(512x512) + bias.
// MODE 0: fp32 A -> fp32 C row-major
// MODE 1: fp32 A -> bf16 C scaled by 0.125, scatter (B,H,S,DK)   [Q]
// MODE 2: fp32 A -> fp32 C scatter (B,H,KL,DK) rows 512..1023    [K/V]
// MODE 3: bf16 A -> fp32 C row-major                             [out proj]
// ---------------------------------------------------------------------------
template<int MODE>
__device__ __forceinline__
void gemm_body(const float* __restrict__ A32, const unsigned short* __restrict__ A16,
               const float* __restrict__ W, const float* __restrict__ bias,
               float* __restrict__ C32, unsigned short* __restrict__ C16) {
    __shared__ float As[64][32];
    __shared__ float Bs[64][32];
    const int t  = threadIdx.x;
    const int bm = blockIdx.y, bn = blockIdx.x;
    const int tm = t >> 4, tn = t & 15;
    float acc[4][4] = {};

    for (int k0 = 0; k0 < 512; k0 += 32) {
        __syncthreads();
        #pragma unroll
        for (int l = 0; l < 2; ++l) {
            int idx = t + (l << 8);              // 0..511
            int row = idx >> 3, c4 = idx & 7;
            if (MODE == 3) {
                ushort4 raw = *(const ushort4*)&A16[((bm << 6) + row) * 512 + k0 + (c4 << 2)];
                float4 f;
                f.x = bf2f(raw.x); f.y = bf2f(raw.y); f.z = bf2f(raw.z); f.w = bf2f(raw.w);
                lds4_32(As, row, c4) = f;
            } else {
                lds4_32(As, row, c4) = *(const float4*)&A32[((bm << 6) + row) * 512 + k0 + (c4 << 2)];
            }
            lds4_32(Bs, row, c4) = *(const float4*)&W[((bn << 6) + row) * 512 + k0 + (c4 << 2)];
        }
        __syncthreads();
        #pragma unroll
        for (int kk4 = 0; kk4 < 8; ++kk4) {
            float4 a4[4], b4[4];
            #pragma unroll
            for (int i = 0; i < 4; ++i) a4[i] = lds4_32(As, tm * 4 + i, kk4);
            #pragma unroll
            for (int j = 0; j < 4; ++j) b4[j] = lds4_32(Bs, tn * 4 + j, kk4);
            #pragma unroll
            for (int i = 0; i < 4; ++i) {
                const float* ap = (const float*)&a4[i];
                #pragma unroll
                for (int j = 0; j < 4; ++j) {
                    const float* bp = (const float*)&b4[j];
                    #pragma unroll
                    for (int u = 0; u < 4; ++u)
                        acc[i][j] = fmaf(ap[u], bp[u], acc[i][j]);
                }
            }
        }
    }

    #pragma unroll
    for (int i = 0; i < 4; ++i) {
        int m = (bm << 6) + tm * 4 + i;
        #pragma unroll
        for (int j = 0; j < 4; ++j) {
            int n = (bn << 6) + tn * 4 + j;
            float val = acc[i][j] + bias[n];
            if (MODE == 0 || MODE == 3) {
                C32[m * 512 + n] = val;
            } else {
                int b = m >> 9, s = m & 511;
                int h = n >> 6, d = n & 63;
                if (MODE == 1) C16[((b * H_ + h) * S_ + s) * DK_ + d] = f2bf(val * 0.125f);
                else           C32[((b * H_ + h) * KL_ + 512 + s) * DK_ + d] = val;
            }
        }
    }
}

__global__ __launch_bounds__(256)
void qkv_gemm_kernel(const float* __restrict__ x,
                     const float* __restrict__ Wq, const float* __restrict__ bq,
                     const float* __restrict__ Wk, const float* __restrict__ bk,
                     const float* __restrict__ Wv, const float* __restrict__ bv,
                     unsigned short* __restrict__ Qb, float* __restrict__ kout,
                     float* __restrict__ vout) {
    if (blockIdx.z == 0)      gemm_body<1>(x, nullptr, Wq, bq, nullptr, Qb);
    else if (blockIdx.z == 1) gemm_body<2>(x, nullptr, Wk, bk, kout, nullptr);
    else                      gemm_body<2>(x, nullptr, Wv, bv, vout, nullptr);
}

__global__ __launch_bounds__(256)
void out_gemm_kernel(const unsigned short* __restrict__ Ob, const float* __restrict__ Wo,
                     const float* __restrict__ bo, float* __restrict__ C) {
    gemm_body<3>(nullptr, Ob, Wo, bo, C, nullptr);
}

// ---------------------------------------------------------------------------
// V^T bf16 mirror: Vt[bh][d][key] <- vout[bh][key][d].  Grid (16 key-tiles, 64 bh).
// ---------------------------------------------------------------------------
__global__ __launch_bounds__(256)
void vt_kernel(const float* __restrict__ vout, unsigned short* __restrict__ Vt) {
    __shared__ float Ls[64][68];
    const int kt = blockIdx.x, bh = blockIdx.y;
    const int t = threadIdx.x;
    const float* Vg = vout + (bh * KL_ + (kt << 6)) * DK_;
    #pragma unroll
    for (int it = 0; it < 4; ++it) {
        int idx = t + (it << 8);
        int row = idx >> 4, c4 = idx & 15;
        *(float4*)&Ls[row][c4 << 2] = *(const float4*)&Vg[row * 64 + (c4 << 2)];
    }
    __syncthreads();
    int d = t >> 2, kp = (t & 3) << 4;          // 16 keys per thread
    unsigned short tmp[16];
    #pragma unroll
    for (int j = 0; j < 16; ++j) tmp[j] = f2bf(Ls[kp + j][d]);
    unsigned short* dst = Vt + (bh * DK_ + d) * KL_ + (kt << 6) + kp;
    *(uint4*)dst       = *(uint4*)tmp;
    *(uint4*)(dst + 8) = *(uint4*)(tmp + 8);
}

// ---------------------------------------------------------------------------
// MFMA flash attention. Block = (qt,h,b), 256 thr = 4 waves, 16 queries/wave.
// Qb bf16 pre-scaled (B,H,S,DK); K fp32 (B,H,KL,DK); Vt bf16 (B,H,DK,KL).
// O bf16 (B,S,H,DK).
// MFMA 16x16x32: A[m=l&15][k=quad*8+j]; B[k=quad*8+j][n=l&15];
//                C/D col=l&15, row=quad*4+reg  [m89/m91].
// ---------------------------------------------------------------------------
__global__ __launch_bounds__(256)
void attn_kernel(const unsigned short* __restrict__ Qb, const float* __restrict__ K,
                 const unsigned short* __restrict__ Vt, unsigned short* __restrict__ O) {
    const int qt = blockIdx.x, h = blockIdx.y, b = blockIdx.z;
    const int bh = b * H_ + h;
    const int t  = threadIdx.x;
    const int l  = t & 63, w = t >> 6;
    const int m16 = l & 15, quad = l >> 4;

    // stride 72 bf16 = 144 B: rows 16B-aligned, bank aliasing <= 2-way (free)
    __shared__ __attribute__((aligned(16))) unsigned short Ks[64][72];
    __shared__ __attribute__((aligned(16))) unsigned short Vts[64][72];
    __shared__ __attribute__((aligned(16))) unsigned short Ps[4][16][72];

    bf16x8 qf[2];
    {
        const unsigned short* qrow = Qb + ((bh * S_) + (qt << 6) + (w << 4) + m16) * DK_;
        qf[0] = *(const bf16x8*)(qrow + quad * 8);
        qf[1] = *(const bf16x8*)(qrow + 32 + quad * 8);
    }

    f32x4 acc_o[4];
    float m_run[4], l_run[4];
    #pragma unroll
    for (int r = 0; r < 4; ++r) {
        m_run[r] = -INFINITY; l_run[r] = 0.f;
        acc_o[r][0] = acc_o[r][1] = acc_o[r][2] = acc_o[r][3] = 0.f;
    }

    const int ktmax = 8 + qt;
    for (int kt = 0; kt <= ktmax; ++kt) {
        __syncthreads();                         // prev-tile frag readers done
        {   // stage K tile (fp32 -> bf16 rows)
            const float* Kg = K + (bh * KL_ + (kt << 6)) * DK_;
            #pragma unroll
            for (int it = 0; it < 4; ++it) {
                int idx = t + (it << 8);         // 0..1023
                int row = idx >> 4, c4 = idx & 15;
                float4 v = *(const float4*)&Kg[row * 64 + (c4 << 2)];
                ushort4 p;
                p.x = f2bf(v.x); p.y = f2bf(v.y); p.z = f2bf(v.z); p.w = f2bf(v.w);
                *(ushort4*)&Ks[row][c4 << 2] = p;
            }
            // stage V^T tile (bf16 direct)
            const unsigned short* Vg = Vt + (bh * DK_) * KL_ + (kt << 6);
            #pragma unroll
            for (int it = 0; it < 2; ++it) {
                int idx = t + (it << 8);         // 0..511
                int row = idx >> 3, c8 = idx & 7;
                *(uint4*)&Vts[row][c8 << 3] = *(const uint4*)&Vg[row * KL_ + (c8 << 3)];
            }
        }
        __syncthreads();

        // ---- S = Q K^T (scale pre-folded into Q) ----
        f32x4 sacc[4];
        #pragma unroll
        for (int nn = 0; nn < 4; ++nn) {
            sacc[nn][0] = sacc[nn][1] = sacc[nn][2] = sacc[nn][3] = 0.f;
            bf16x8 kf0 = *(const bf16x8*)&Ks[(nn << 4) + m16][quad * 8];
            bf16x8 kf1 = *(const bf16x8*)&Ks[(nn << 4) + m16][32 + quad * 8];
            sacc[nn] = __builtin_amdgcn_mfma_f32_16x16x32_bf16(qf[0], kf0, sacc[nn], 0, 0, 0);
            sacc[nn] = __builtin_amdgcn_mfma_f32_16x16x32_bf16(qf[1], kf1, sacc[nn], 0, 0, 0);
        }

        if (kt == ktmax) {                       // only the diagonal tile masks
            int kbase  = (kt << 6) + m16;        // + nn*16 -> key index
            int qg512  = (qt << 6) + (w << 4) + (quad << 2) + 512;  // + r
            #pragma unroll
            for (int nn = 0; nn < 4; ++nn)
                #pragma unroll
                for (int r = 0; r < 4; ++r)
                    if (kbase + (nn << 4) > qg512 + r) sacc[nn][r] = -INFINITY;
        }

        // ---- online softmax (rows = quad*4+r, reduce over 16 lanes of quad) ----
        float mnew[4], alpha[4];
        #pragma unroll
        for (int r = 0; r < 4; ++r) {
            float mx = fmaxf(fmaxf(sacc[0][r], sacc[1][r]), fmaxf(sacc[2][r], sacc[3][r]));
            mx = fmaxf(mx, __shfl_xor(mx, 1));
            mx = fmaxf(mx, __shfl_xor(mx, 2));
            mx = fmaxf(mx, __shfl_xor(mx, 4));
            mx = fmaxf(mx, __shfl_xor(mx, 8));
            mnew[r]  = fmaxf(m_run[r], mx);
            alpha[r] = __expf(m_run[r] - mnew[r]);   // first tile: exp(-inf)=0
            m_run[r] = mnew[r];
        }
        #pragma unroll
        for (int r = 0; r < 4; ++r) {
            float ps = 0.f;
            #pragma unroll
            for (int nn = 0; nn < 4; ++nn) {
                float p = __expf(sacc[nn][r] - mnew[r]);
                ps += p;
                Ps[w][(quad << 2) + r][(nn << 4) + m16] = f2bf(p);
            }
            ps += __shfl_xor(ps, 1);
            ps += __shfl_xor(ps, 2);
            ps += __shfl_xor(ps, 4);
            ps += __shfl_xor(ps, 8);
            l_run[r] = l_run[r] * alpha[r] + ps;
        }
        #pragma unroll
        for (int nn = 0; nn < 4; ++nn)
            #pragma unroll
            for (int r = 0; r < 4; ++r) acc_o[nn][r] *= alpha[r];

        // ---- O += P V  (P via LDS round-trip to A-layout; same-wave, in-order) ----
        bf16x8 pf0 = *(const bf16x8*)&Ps[w][m16][quad * 8];
        bf16x8 pf1 = *(const bf16x8*)&Ps[w][m16][32 + quad * 8];
        #pragma unroll
        for (int nn = 0; nn < 4; ++nn) {
            bf16x8 vf0 = *(const bf16x8*)&Vts[(nn << 4) + m16][quad * 8];
            bf16x8 vf1 = *(const bf16x8*)&Vts[(nn << 4) + m16][32 + quad * 8];
            acc_o[nn] = __builtin_amdgcn_mfma_f32_16x16x32_bf16(pf0, vf0, acc_o[nn], 0, 0, 0);
            acc_o[nn] = __builtin_amdgcn_mfma_f32_16x16x32_bf16(pf1, vf1, acc_o[nn], 0, 0, 0);
        }
    }

    // epilogue: O[(b*512+q)*512 + h*64 + d] bf16, row=quad*4+r, col=nn*16+m16
    unsigned short* Og = O + (b * S_ + (qt << 6) + (w << 4)) * D_ + (h << 6);
    #pragma unroll
    for (int r = 0; r < 4; ++r) {
        float inv = 1.f / l_run[r];
        #pragma unroll
        for (int nn = 0; nn < 4; ++nn)
            Og[((quad << 2) + r) * D_ + (nn << 4) + m16] = f2bf(acc_o[nn][r] * inv);
    }
}

// ---------------------------------------------------------------------------
extern "C" void kernel_launch(void* const* d_in, const int* in_sizes, int n_in,
                              void* d_out, int out_size, void* d_ws, size_t ws_size,
                              hipStream_t stream) {
    const float* x  = (const float*)d_in[0];
    const float* pk = (const float*)d_in[1];
    const float* pv = (const float*)d_in[2];
    const float* Wq = (const float*)d_in[3];
    const float* bq = (const float*)d_in[4];
    const float* Wk = (const float*)d_in[5];
    const float* bk = (const float*)d_in[6];
    const float* Wv = (const float*)d_in[7];
    const float* bv = (const float*)d_in[8];
    const float* Wo = (const float*)d_in[9];
    const float* bo = (const float*)d_in[10];

    float* out     = (float*)d_out;            // (8,512,512)
    float* kout    = out + 2097152;            // (8,8,1024,64)
    float* vout    = kout + 4194304;           // (8,8,1024,64)
    float* off_out = vout + 4194304;           // scalar 1024.0

    unsigned short* Qb = (unsigned short*)d_ws;      // 2M bf16 = 4 MB (q/8)
    unsigned short* Vt = Qb + 2097152;               // 4M bf16 = 8 MB (V^T)
    unsigned short* Ob = Vt + 4194304;               // 2M bf16 = 4 MB (attn out)

    copy_prev_kernel<<<2048, 256, 0, stream>>>((const float4*)pk, (const float4*)pv,
                                               (float4*)kout, (float4*)vout, off_out);
    qkv_gemm_kernel<<<dim3(8, 64, 3), 256, 0, stream>>>(x, Wq, bq, Wk, bk, Wv, bv,
                                                        Qb, kout, vout);
    vt_kernel<<<dim3(16, 64), 256, 0, stream>>>(vout, Vt);
    attn_kernel<<<dim3(8, 8, 8), 256, 0, stream>>>(Qb, kout, Vt, Ob);
    out_gemm_kernel<<<dim3(8, 64), 256, 0, stream>>>(Ob, Wo, bo, out);
}

// Round 3
// 190.934 us; speedup vs baseline: 3.2702x; 1.6895x over previous
//
#include <hip/hip_runtime.h>
#include <math.h>

#define B_  8
#define S_  512
#define D_  512
#define H_  8
#define DK_ 64
#define KL_ 1024

typedef __attribute__((ext_vector_type(8))) short bf16x8;
typedef __attribute__((ext_vector_type(4))) float f32x4;

__device__ __forceinline__ unsigned short f2bf(float f) {
    unsigned u = __float_as_uint(f);
    u += 0x7FFF + ((u >> 16) & 1);          // RNE
    return (unsigned short)(u >> 16);
}
__device__ __forceinline__ float bf2f(unsigned short h) {
    return __uint_as_float(((unsigned)h) << 16);
}

// async global->LDS, 16 B per lane; LDS dest = wave-uniform base + lane*16
__device__ __forceinline__ void gld16(const void* g, void* l) {
    __builtin_amdgcn_global_load_lds(
        (const __attribute__((address_space(1))) unsigned int*)g,
        (__attribute__((address_space(3))) unsigned int*)l, 16, 0, 0);
}

// ---------------------------------------------------------------------------
// Cache shift: k_out[:, :, 0:512, :] = prev_k[:, :, 512:1024, :]; same for v.
// Writes new_offset (=1024) as float.
// ---------------------------------------------------------------------------
__global__ __launch_bounds__(256)
void copy_prev_kernel(const float4* __restrict__ pk, const float4* __restrict__ pv,
                      float4* __restrict__ kout, float4* __restrict__ vout,
                      float* __restrict__ off_out) {
    int i = blockIdx.x * 256 + threadIdx.x;     // 0 .. 524287
    int bh = i >> 13;                           // b*H+h (64)
    int r4 = i & 8191;                          // 512 rows * 16 f4
    kout[bh * 16384 + r4] = pk[bh * 16384 + 8192 + r4];
    vout[bh * 16384 + r4] = pv[bh * 16384 + 8192 + r4];
    if (i == 0) off_out[0] = 1024.0f;
}

// ---------------------------------------------------------------------------
// fp32 -> bf16 conversion for x, Wq, Wk, Wv (8 elements/thread).
// ---------------------------------------------------------------------------
__global__ __launch_bounds__(256)
void convert_kernel(const float* __restrict__ x,  const float* __restrict__ Wq,
                    const float* __restrict__ Wk, const float* __restrict__ Wv,
                    unsigned short* __restrict__ xb, unsigned short* __restrict__ Wqb,
                    unsigned short* __restrict__ Wkb, unsigned short* __restrict__ Wvb) {
    int i = blockIdx.x * 256 + threadIdx.x;     // 0 .. 360447
    const float* src; unsigned short* dst; int off;
    if (i < 262144)      { src = x;  dst = xb;  off = i; }
    else if (i < 294912) { src = Wq; dst = Wqb; off = i - 262144; }
    else if (i < 327680) { src = Wk; dst = Wkb; off = i - 294912; }
    else                 { src = Wv; dst = Wvb; off = i - 327680; }
    float4 v0 = ((const float4*)src)[off * 2];
    float4 v1 = ((const float4*)src)[off * 2 + 1];
    unsigned short tmp[8] = {f2bf(v0.x), f2bf(v0.y), f2bf(v0.z), f2bf(v0.w),
                             f2bf(v1.x), f2bf(v1.y), f2bf(v1.z), f2bf(v1.w)};
    *(uint4*)&dst[off * 8] = *(uint4*)tmp;
}

// ---------------------------------------------------------------------------
// m97-style MFMA GEMM: C(4096x512) = A_bf16 @ W^T + bias.
// 128x128 block tile, 4 waves 2x2, each wave 4x4 of 16x16x32 MFMAs, BK=32.
// A row-major bf16 (K inner). W row-major (N x K): bf16 (async) or fp32
// (register-staged + convert, MODE 3).
// MODE 1: bf16 C scaled 0.125, scatter (B,H,S,DK)    [Q]
// MODE 2: fp32 C scatter (B,H,KL,DK) rows 512..1023  [K/V]
// MODE 3: fp32 C row-major, fp32 W                   [out proj]
// ---------------------------------------------------------------------------
template<int MODE>
__device__ __forceinline__
void mfma_gemm_body(const unsigned short* __restrict__ A,
                    const unsigned short* __restrict__ Wb,
                    const float* __restrict__ Wf,
                    const float* __restrict__ bias,
                    float* __restrict__ C32, unsigned short* __restrict__ C16) {
    __shared__ unsigned short As[128 * 32];
    __shared__ unsigned short Bs[128 * 32];
    const int t = threadIdx.x, l = t & 63, w = t >> 6;
    const int m16 = l & 15, quad = l >> 4;
    const int wm = w >> 1, wn = w & 1;
    const int bn = blockIdx.x, bm = blockIdx.y;
    const int arow = l >> 2, acol = (l & 3) * 8;   // 4 lanes / 64B row

    f32x4 acc[4][4] = {};

    const unsigned short* Ag = A + (bm * 128) * 512;

    for (int k0 = 0; k0 < 512; k0 += 32) {
        __syncthreads();                            // prev-iter frag readers done
        #pragma unroll
        for (int q = 0; q < 2; ++q) {
            int chunk = w * 2 + q;                  // 16 rows (1 KB) per chunk
            gld16(Ag + (chunk * 16 + arow) * 512 + k0 + acol,
                  &As[chunk * 512 + l * 8]);
        }
        if (MODE == 3) {
            const float* Wg = Wf + (bn * 128) * 512 + k0;
            #pragma unroll
            for (int q = 0; q < 2; ++q) {
                int chunk = w * 2 + q;
                const float* src = Wg + (chunk * 16 + arow) * 512 + acol;
                float4 v0 = *(const float4*)src;
                float4 v1 = *(const float4*)(src + 4);
                unsigned short tmp[8] = {f2bf(v0.x), f2bf(v0.y), f2bf(v0.z), f2bf(v0.w),
                                         f2bf(v1.x), f2bf(v1.y), f2bf(v1.z), f2bf(v1.w)};
                *(uint4*)&Bs[chunk * 512 + l * 8] = *(uint4*)tmp;
            }
        } else {
            const unsigned short* Wg = Wb + (bn * 128) * 512 + k0;
            #pragma unroll
            for (int q = 0; q < 2; ++q) {
                int chunk = w * 2 + q;
                gld16(Wg + (chunk * 16 + arow) * 512 + acol,
                      &Bs[chunk * 512 + l * 8]);
            }
        }
        __syncthreads();                            // vmcnt(0) drain + barrier

        bf16x8 af[4], bfr[4];
        #pragma unroll
        for (int mm = 0; mm < 4; ++mm)
            af[mm] = *(const bf16x8*)&As[(wm * 64 + mm * 16 + m16) * 32 + quad * 8];
        #pragma unroll
        for (int nn = 0; nn < 4; ++nn)
            bfr[nn] = *(const bf16x8*)&Bs[(wn * 64 + nn * 16 + m16) * 32 + quad * 8];
        #pragma unroll
        for (int mm = 0; mm < 4; ++mm)
            #pragma unroll
            for (int nn = 0; nn < 4; ++nn)
                acc[mm][nn] = __builtin_amdgcn_mfma_f32_16x16x32_bf16(
                    af[mm], bfr[nn], acc[mm][nn], 0, 0, 0);
    }

    // epilogue: C row = quad*4+r, col = m16 within each 16x16 tile [m89/m91]
    #pragma unroll
    for (int mm = 0; mm < 4; ++mm) {
        #pragma unroll
        for (int nn = 0; nn < 4; ++nn) {
            int n = bn * 128 + wn * 64 + nn * 16 + m16;
            float bv_ = bias[n];
            #pragma unroll
            for (int r = 0; r < 4; ++r) {
                int m = bm * 128 + wm * 64 + mm * 16 + quad * 4 + r;
                float val = acc[mm][nn][r] + bv_;
                if (MODE == 3) {
                    C32[m * 512 + n] = val;
                } else {
                    int b = m >> 9, s = m & 511;
                    int h = n >> 6, d = n & 63;
                    if (MODE == 1) C16[((b * H_ + h) * S_ + s) * DK_ + d] = f2bf(val * 0.125f);
                    else           C32[((b * H_ + h) * KL_ + 512 + s) * DK_ + d] = val;
                }
            }
        }
    }
}

__global__ __launch_bounds__(256)
void qkv_mfma_kernel(const unsigned short* __restrict__ xb,
                     const unsigned short* __restrict__ Wqb, const float* __restrict__ bq,
                     const unsigned short* __restrict__ Wkb, const float* __restrict__ bk,
                     const unsigned short* __restrict__ Wvb, const float* __restrict__ bv,
                     unsigned short* __restrict__ Qb, float* __restrict__ kout,
                     float* __restrict__ vout) {
    if (blockIdx.z == 0)      mfma_gemm_body<1>(xb, Wqb, nullptr, bq, nullptr, Qb);
    else if (blockIdx.z == 1) mfma_gemm_body<2>(xb, Wkb, nullptr, bk, kout, nullptr);
    else                      mfma_gemm_body<2>(xb, Wvb, nullptr, bv, vout, nullptr);
}

__global__ __launch_bounds__(256)
void out_mfma_kernel(const unsigned short* __restrict__ Ob, const float* __restrict__ Wo,
                     const float* __restrict__ bo, float* __restrict__ C) {
    mfma_gemm_body<3>(Ob, nullptr, Wo, bo, C, nullptr);
}

// ---------------------------------------------------------------------------
// V^T bf16 mirror: Vt[bh][d][key] <- vout[bh][key][d].  Grid (16 key-tiles, 64 bh).
// ---------------------------------------------------------------------------
__global__ __launch_bounds__(256)
void vt_kernel(const float* __restrict__ vout, unsigned short* __restrict__ Vt) {
    __shared__ float Ls[64][68];
    const int kt = blockIdx.x, bh = blockIdx.y;
    const int t = threadIdx.x;
    const float* Vg = vout + (bh * KL_ + (kt << 6)) * DK_;
    #pragma unroll
    for (int it = 0; it < 4; ++it) {
        int idx = t + (it << 8);
        int row = idx >> 4, c4 = idx & 15;
        *(float4*)&Ls[row][c4 << 2] = *(const float4*)&Vg[row * 64 + (c4 << 2)];
    }
    __syncthreads();
    int d = t >> 2, kp = (t & 3) << 4;          // 16 keys per thread
    unsigned short tmp[16];
    #pragma unroll
    for (int j = 0; j < 16; ++j) tmp[j] = f2bf(Ls[kp + j][d]);
    unsigned short* dst = Vt + (bh * DK_ + d) * KL_ + (kt << 6) + kp;
    *(uint4*)dst       = *(uint4*)tmp;
    *(uint4*)(dst + 8) = *(uint4*)(tmp + 8);
}

// ---------------------------------------------------------------------------
// MFMA flash attention (unchanged from round 2).
// ---------------------------------------------------------------------------
__global__ __launch_bounds__(256)
void attn_kernel(const unsigned short* __restrict__ Qb, const float* __restrict__ K,
                 const unsigned short* __restrict__ Vt, unsigned short* __restrict__ O) {
    const int qt = blockIdx.x, h = blockIdx.y, b = blockIdx.z;
    const int bh = b * H_ + h;
    const int t  = threadIdx.x;
    const int l  = t & 63, w = t >> 6;
    const int m16 = l & 15, quad = l >> 4;

    __shared__ __attribute__((aligned(16))) unsigned short Ks[64][72];
    __shared__ __attribute__((aligned(16))) unsigned short Vts[64][72];
    __shared__ __attribute__((aligned(16))) unsigned short Ps[4][16][72];

    bf16x8 qf[2];
    {
        const unsigned short* qrow = Qb + ((bh * S_) + (qt << 6) + (w << 4) + m16) * DK_;
        qf[0] = *(const bf16x8*)(qrow + quad * 8);
        qf[1] = *(const bf16x8*)(qrow + 32 + quad * 8);
    }

    f32x4 acc_o[4];
    float m_run[4], l_run[4];
    #pragma unroll
    for (int r = 0; r < 4; ++r) {
        m_run[r] = -INFINITY; l_run[r] = 0.f;
        acc_o[r][0] = acc_o[r][1] = acc_o[r][2] = acc_o[r][3] = 0.f;
    }

    const int ktmax = 8 + qt;
    for (int kt = 0; kt <= ktmax; ++kt) {
        __syncthreads();
        {   // stage K tile (fp32 -> bf16 rows)
            const float* Kg = K + (bh * KL_ + (kt << 6)) * DK_;
            #pragma unroll
            for (int it = 0; it < 4; ++it) {
                int idx = t + (it << 8);
                int row = idx >> 4, c4 = idx & 15;
                float4 v = *(const float4*)&Kg[row * 64 + (c4 << 2)];
                ushort4 p;
                p.x = f2bf(v.x); p.y = f2bf(v.y); p.z = f2bf(v.z); p.w = f2bf(v.w);
                *(ushort4*)&Ks[row][c4 << 2] = p;
            }
            const unsigned short* Vg = Vt + (bh * DK_) * KL_ + (kt << 6);
            #pragma unroll
            for (int it = 0; it < 2; ++it) {
                int idx = t + (it << 8);
                int row = idx >> 3, c8 = idx & 7;
                *(uint4*)&Vts[row][c8 << 3] = *(const uint4*)&Vg[row * KL_ + (c8 << 3)];
            }
        }
        __syncthreads();

        f32x4 sacc[4];
        #pragma unroll
        for (int nn = 0; nn < 4; ++nn) {
            sacc[nn][0] = sacc[nn][1] = sacc[nn][2] = sacc[nn][3] = 0.f;
            bf16x8 kf0 = *(const bf16x8*)&Ks[(nn << 4) + m16][quad * 8];
            bf16x8 kf1 = *(const bf16x8*)&Ks[(nn << 4) + m16][32 + quad * 8];
            sacc[nn] = __builtin_amdgcn_mfma_f32_16x16x32_bf16(qf[0], kf0, sacc[nn], 0, 0, 0);
            sacc[nn] = __builtin_amdgcn_mfma_f32_16x16x32_bf16(qf[1], kf1, sacc[nn], 0, 0, 0);
        }

        if (kt == ktmax) {
            int kbase = (kt << 6) + m16;
            int qg512 = (qt << 6) + (w << 4) + (quad << 2) + 512;
            #pragma unroll
            for (int nn = 0; nn < 4; ++nn)
                #pragma unroll
                for (int r = 0; r < 4; ++r)
                    if (kbase + (nn << 4) > qg512 + r) sacc[nn][r] = -INFINITY;
        }

        float mnew[4], alpha[4];
        #pragma unroll
        for (int r = 0; r < 4; ++r) {
            float mx = fmaxf(fmaxf(sacc[0][r], sacc[1][r]), fmaxf(sacc[2][r], sacc[3][r]));
            mx = fmaxf(mx, __shfl_xor(mx, 1));
            mx = fmaxf(mx, __shfl_xor(mx, 2));
            mx = fmaxf(mx, __shfl_xor(mx, 4));
            mx = fmaxf(mx, __shfl_xor(mx, 8));
            mnew[r]  = fmaxf(m_run[r], mx);
            alpha[r] = __expf(m_run[r] - mnew[r]);
            m_run[r] = mnew[r];
        }
        #pragma unroll
        for (int r = 0; r < 4; ++r) {
            float ps = 0.f;
            #pragma unroll
            for (int nn = 0; nn < 4; ++nn) {
                float p = __expf(sacc[nn][r] - mnew[r]);
                ps += p;
                Ps[w][(quad << 2) + r][(nn << 4) + m16] = f2bf(p);
            }
            ps += __shfl_xor(ps, 1);
            ps += __shfl_xor(ps, 2);
            ps += __shfl_xor(ps, 4);
            ps += __shfl_xor(ps, 8);
            l_run[r] = l_run[r] * alpha[r] + ps;
        }
        #pragma unroll
        for (int nn = 0; nn < 4; ++nn)
            #pragma unroll
            for (int r = 0; r < 4; ++r) acc_o[nn][r] *= alpha[r];

        bf16x8 pf0 = *(const bf16x8*)&Ps[w][m16][quad * 8];
        bf16x8 pf1 = *(const bf16x8*)&Ps[w][m16][32 + quad * 8];
        #pragma unroll
        for (int nn = 0; nn < 4; ++nn) {
            bf16x8 vf0 = *(const bf16x8*)&Vts[(nn << 4) + m16][quad * 8];
            bf16x8 vf1 = *(const bf16x8*)&Vts[(nn << 4) + m16][32 + quad * 8];
            acc_o[nn] = __builtin_amdgcn_mfma_f32_16x16x32_bf16(pf0, vf0, acc_o[nn], 0, 0, 0);
            acc_o[nn] = __builtin_amdgcn_mfma_f32_16x16x32_bf16(pf1, vf1, acc_o[nn], 0, 0, 0);
        }
    }

    unsigned short* Og = O + (b * S_ + (qt << 6) + (w << 4)) * D_ + (h << 6);
    #pragma unroll
    for (int r = 0; r < 4; ++r) {
        float inv = 1.f / l_run[r];
        #pragma unroll
        for (int nn = 0; nn < 4; ++nn)
            Og[((quad << 2) + r) * D_ + (nn << 4) + m16] = f2bf(acc_o[nn][r] * inv);
    }
}

// ---------------------------------------------------------------------------
extern "C" void kernel_launch(void* const* d_in, const int* in_sizes, int n_in,
                              void* d_out, int out_size, void* d_ws, size_t ws_size,
                              hipStream_t stream) {
    const float* x  = (const float*)d_in[0];
    const float* pk = (const float*)d_in[1];
    const float* pv = (const float*)d_in[2];
    const float* Wq = (const float*)d_in[3];
    const float* bq = (const float*)d_in[4];
    const float* Wk = (const float*)d_in[5];
    const float* bk = (const float*)d_in[6];
    const float* Wv = (const float*)d_in[7];
    const float* bv = (const float*)d_in[8];
    const float* Wo = (const float*)d_in[9];
    const float* bo = (const float*)d_in[10];

    float* out     = (float*)d_out;            // (8,512,512)
    float* kout    = out + 2097152;            // (8,8,1024,64)
    float* vout    = kout + 4194304;           // (8,8,1024,64)
    float* off_out = vout + 4194304;           // scalar 1024.0

    // 16 MB workspace budget with lifetime-based aliasing:
    unsigned short* Qb  = (unsigned short*)d_ws;   // [0,4MB)   live: qkv..attn
    unsigned short* Vt  = Qb + 2097152;            // [4,12MB)  live: vt..attn
    unsigned short* xb  = Vt + 4194304;            // [12,16MB) live: convert..qkv
    unsigned short* Ob  = xb;                      // alias: attn..out (xb dead)
    unsigned short* Wqb = Vt;                      // alias inside Vt: dead before vt
    unsigned short* Wkb = Wqb + 262144;
    unsigned short* Wvb = Wkb + 262144;

    convert_kernel<<<1408, 256, 0, stream>>>(x, Wq, Wk, Wv, xb, Wqb, Wkb, Wvb);
    copy_prev_kernel<<<2048, 256, 0, stream>>>((const float4*)pk, (const float4*)pv,
                                               (float4*)kout, (float4*)vout, off_out);
    qkv_mfma_kernel<<<dim3(4, 32, 3), 256, 0, stream>>>(xb, Wqb, bq, Wkb, bk, Wvb, bv,
                                                        Qb, kout, vout);
    vt_kernel<<<dim3(16, 64), 256, 0, stream>>>(vout, Vt);
    attn_kernel<<<dim3(8, 8, 8), 256, 0, stream>>>(Qb, kout, Vt, Ob);
    out_mfma_kernel<<<dim3(4, 32), 256, 0, stream>>>(Ob, Wo, bo, out);
}